// Round 15
// baseline (59.613 us; speedup 1.0000x reference)
//
#include <hip/hip_runtime.h>
#include <cstdint>

#define NROI 2048
#define NCLS 21
#define NFG  20
#define CPAD 128          // survivor slots per class (>= top_k=100)
#define CTOT (NFG * CPAD) // 2560
#define NTHR 1024         // threads per NMS block (16 waves)
#define SBLK 256          // rows per NMS stage
#define RSEL 480          // selection rank target per window
#define SCAP 512          // selection capacity (sorted window size)
#define CSEL 512          // contender cap for top-k rank-count
#define DROWS 64          // rows per decode block
#define INVH 0xFF800000u  // desc_key(-inf) == invalid marker

typedef unsigned long long u64;
typedef unsigned int u32;

// ---- sortable key helpers -------------------------------------------------
// desc_key(s): larger float -> smaller uint, so ascending sort on
// u64 key = (desc_key(score)<<32)|index == (score desc, index asc).
__device__ __forceinline__ u32 desc_key(float s) {
  u32 u = __float_as_uint(s);
  u32 asc = (u & 0x80000000u) ? ~u : (u | 0x80000000u);
  return ~asc;
}
__device__ __forceinline__ float key_to_float(u32 desc) {
  u32 asc = ~desc;
  u32 u = (asc & 0x80000000u) ? (asc ^ 0x80000000u) : ~asc;
  return __uint_as_float(u);
}
__device__ __forceinline__ u64 shflx_u64(u64 v, int m) {
  u32 lo = (u32)v, hi = (u32)(v >> 32);
  lo = (u32)__shfl_xor((int)lo, m);
  hi = (u32)__shfl_xor((int)hi, m);
  return ((u64)hi << 32) | (u64)lo;
}
// bitonic compare-exchange for element i at pass (k, j), u64 lex order
__device__ __forceinline__ void cmpex64(u64& mine, u64 other, int i, int j, int k) {
  bool amIlow = ((i & j) == 0);
  bool dir = ((i & k) == 0);
  bool otherLess = other < mine;
  if (otherLess != (amIlow != dir)) mine = other;
}

// wave-0 parallel 256-bin bucket select: smallest bucket b with
// cum(h[0..b]) >= need; *outC = cum before b. (1 <= need <= total)
__device__ __forceinline__ void bucket_select(const int* h, int need, int lane,
                                              int* outB, int* outC) {
  int base = lane << 2;
  int c0 = h[base], c1 = h[base + 1], c2 = h[base + 2], c3 = h[base + 3];
  int s = c0 + c1 + c2 + c3;
  int pre = s;
  #pragma unroll
  for (int off = 1; off < 64; off <<= 1) {
    int v = __shfl_up(pre, off);
    if (lane >= off) pre += v;
  }
  u64 ball = __ballot(pre >= need);
  int ln = __ffsll((long long)ball) - 1;
  int exc = __shfl(pre, ln) - __shfl(s, ln);
  int b0 = __shfl(c0, ln), b1 = __shfl(c1, ln), b2 = __shfl(c2, ln);
  int bkt, cb;
  if (exc + b0 >= need)                { bkt = (ln << 2) + 0; cb = exc; }
  else if (exc + b0 + b1 >= need)      { bkt = (ln << 2) + 1; cb = exc + b0; }
  else if (exc + b0 + b1 + b2 >= need) { bkt = (ln << 2) + 2; cb = exc + b0 + b1; }
  else                                 { bkt = (ln << 2) + 3; cb = exc + b0 + b1 + b2; }
  if (lane == 0) { *outB = bkt; *outC = cb; }
}

// ---- phase 1: coalesced softmax + argmax + decode (32 blocks x 64 thr) ----
__global__ __launch_bounds__(64)
void k_decode(const float* __restrict__ rois,
              const float* __restrict__ locs,
              const float* __restrict__ scores,
              float* __restrict__ probsT,     // [NFG][NROI]: class c+1 -> row c
              float4* __restrict__ decoded,
              u32* __restrict__ done) {
  __shared__ float srow[DROWS][NCLS + 2];   // stride 23 (odd) -> conflict-free
  const int tid = threadIdx.x;
  const int rbase = blockIdx.x * DROWS;
  if (rbase == 0 && tid == 0) *done = 0u;   // reset last-block counter each launch

  const float* src = scores + (size_t)rbase * NCLS;
  for (int t = tid; t < DROWS * NCLS; t += 64)
    srow[t / NCLS][t % NCLS] = src[t];
  __syncthreads();

  const int r = rbase + tid;
  float s[NCLS];
  #pragma unroll
  for (int c = 0; c < NCLS; ++c) s[c] = srow[tid][c];
  float m = s[0];
  #pragma unroll
  for (int c = 0; c < NCLS; ++c) m = fmaxf(m, s[c]);
  float sum = 0.0f;
  #pragma unroll
  for (int c = 0; c < NCLS; ++c) { s[c] = expf(s[c] - m); sum += s[c]; }

  float pb = s[0] / sum; int best = 0;
  #pragma unroll
  for (int c = 1; c < NCLS; ++c) {
    float p = s[c] / sum;
    probsT[(c - 1) * NROI + r] = p;        // coalesced store per class
    if (p > pb) { pb = p; best = c; }      // strict > == first-index argmax
  }

  float4 roi = ((const float4*)rois)[r];
  float pcx = __fmul_rn(__fadd_rn(roi.x, roi.z), 0.5f);
  float pcy = __fmul_rn(__fadd_rn(roi.y, roi.w), 0.5f);
  float pw  = __fsub_rn(roi.z, roi.x);
  float ph  = __fsub_rn(roi.w, roi.y);

  float4 gl = ((const float4*)locs)[r * NCLS + best];   // 16B-aligned
  float g0 = gl.x / 10.0f;
  float g1 = gl.y / 10.0f;
  float g2 = gl.z / 20.0f;
  float g3 = gl.w / 20.0f;

  // no-FMA-contraction decode to match numpy rounding
  float cx = __fadd_rn(__fmul_rn(g0, pw), pcx);
  float cy = __fadd_rn(__fmul_rn(g1, ph), pcy);
  float w  = __fmul_rn(expf(g2), pw);
  float h  = __fmul_rn(expf(g3), ph);
  float hw = __fmul_rn(w, 0.5f);
  float hh = __fmul_rn(h, 0.5f);
  decoded[r] = make_float4(__fsub_rn(cx, hw), __fsub_rn(cy, hh),
                           __fadd_rn(cx, hw), __fadd_rn(cy, hh));
}

// ---- phase 2: select+sort window -> 2-stage bitmask NMS (overlapped) ------
__global__ __launch_bounds__(NTHR)
void k_nms(const float* __restrict__ probsT,
           const float4* __restrict__ decoded,
           const float* __restrict__ min_score_p,
           const float* __restrict__ max_overlap_p,
           u64* __restrict__ cand,
           float4* __restrict__ cbox,
           u32* __restrict__ done,
           float* __restrict__ out,
           const int* __restrict__ top_k_p) {
  // LDS word map (u32), ~42.5 KB total:
  //  [0,1024)     mbA u64[512]        (sort mailbox A; tail: kk[0..])
  //  [1024,2048)  mbB u64[512]        (sort mailbox B)
  //  [2048,3072)  skeyW u64[512]      (sorted window keys)
  //  [3072,5120)  maskW u64[256*4]    (stage-1 masks)
  //  [5120,6400)  stage1 SoA bx0/by0/bx1/by1/areaA [256]    (tail: ck@5120)
  //  [6400,7040)  surv SoA sx0/sy0/sx1/sy1/sarea [128] each
  //  [7040,7168)  survKeyH[128]
  //  [7168,7296)  survRows[128]
  //  [7296,8576)  stage2 SoA bx0B/by0B/bx1B/by1B/areaB [256]
  //  [8576,10624) maskWB u64[256*4]   (stage-2 masks)
  __shared__ u32 LDSW[10624];
  __shared__ u64 remInitW[4];
  __shared__ int hist1[256], hist2[256];
  __shared__ int cntLds, scLds, cSelSh, selB1, selC1, selB2, selD2, mSh, cCnt;
  __shared__ u32 lastSh;

  u64* mbAu    = (u64*)(LDSW + 0);
  u64* mbBu    = (u64*)(LDSW + 1024);
  u64* skeyW64 = (u64*)(LDSW + 2048);
  u64* maskW   = (u64*)(LDSW + 3072);
  float* bx0   = (float*)(LDSW + 5120);
  float* by0   = (float*)(LDSW + 5376);
  float* bx1   = (float*)(LDSW + 5632);
  float* by1   = (float*)(LDSW + 5888);
  float* areaA = (float*)(LDSW + 6144);
  float* sx0   = (float*)(LDSW + 6400);
  float* sy0   = (float*)(LDSW + 6528);
  float* sx1   = (float*)(LDSW + 6656);
  float* sy1   = (float*)(LDSW + 6784);
  float* sarea = (float*)(LDSW + 6912);
  u32* survKeyH = LDSW + 7040;
  u32* survRows = LDSW + 7168;
  float* bx0B  = (float*)(LDSW + 7296);
  float* by0B  = (float*)(LDSW + 7552);
  float* bx1B  = (float*)(LDSW + 7808);
  float* by1B  = (float*)(LDSW + 8064);
  float* areaB = (float*)(LDSW + 8320);
  u64* maskWB  = (u64*)(LDSW + 8576);

  const int cls = blockIdx.x;
  const int tid = threadIdx.x;
  const int lane = tid & 63;
  const int wid = tid >> 6;
  const float msc = *min_score_p;
  const float ovr = *max_overlap_p;
  const int K = *top_k_p;
  const int Kcap = (K < CPAD) ? K : CPAD;

  if (tid == 0) { cntLds = 0; scLds = 0; }
  __syncthreads();

  // ---- per-thread keys (2 rows each) + valid count ----
  float p0v = probsT[cls * NROI + tid];
  float p1v = probsT[cls * NROI + tid + 1024];
  bool v0 = p0v > msc, v1 = p1v > msc;
  u64 kq0 = ((u64)desc_key(v0 ? p0v : -__builtin_inff()) << 32) | (u32)tid;
  u64 kq1 = ((u64)desc_key(v1 ? p1v : -__builtin_inff()) << 32) | (u32)(tid + 1024);
  {
    u64 ba = __ballot(v0), bb = __ballot(v1);
    if (lane == 0) atomicAdd(&cntLds, __popcll(ba) + __popcll(bb));
  }
  __syncthreads();
  const int nv = cntLds;

  int sc = 0;
  int processed = 0;
  u64 minKey = 0ULL;   // exclusive lower bound of already-processed keys

  // wave-0 sweep over one stage's mask buffer (linear scan, 4-row prefetch)
  auto sweep = [&](const u64* MW, int RL, int sbase) {
    int t0 = RL;
    u64 rw0 = (t0 <= 0) ? ~0ULL : ((t0 >= 64) ? 0ULL : (~0ULL << t0));
    int t1 = t0 - 64;
    u64 rw1 = (t1 <= 0) ? ~0ULL : ((t1 >= 64) ? 0ULL : (~0ULL << t1));
    int t2 = t0 - 128;
    u64 rw2 = (t2 <= 0) ? ~0ULL : ((t2 >= 64) ? 0ULL : (~0ULL << t2));
    int t3 = t0 - 192;
    u64 rw3 = (t3 <= 0) ? ~0ULL : ((t3 >= 64) ? 0ULL : (~0ULL << t3));
    rw0 |= remInitW[0]; rw1 |= remInitW[1];
    rw2 |= remInitW[2]; rw3 |= remInitW[3];
    int scW = sc;
    bool full = scW >= Kcap;
    u64 a00,a01,a02,a03,a10,a11,a12,a13,a20,a21,a22,a23,a30,a31,a32,a33;
    u64 b00,b01,b02,b03,b10,b11,b12,b13,b20,b21,b22,b23,b30,b31,b32,b33;
#define LD4(V0,V1,V2,V3,R) { int rr_ = (R); \
    V0 = MW[(rr_<<2)+0]; V1 = MW[(rr_<<2)+1]; \
    V2 = MW[(rr_<<2)+2]; V3 = MW[(rr_<<2)+3]; }
#define PRX(RWG, BIT, M0,M1,M2,M3, ROW) \
    if (!full && !(((RWG) >> (BIT)) & 1ULL)) { \
      rw0 |= (M0); rw1 |= (M1); rw2 |= (M2); rw3 |= (M3); \
      if (lane == 0) survRows[scW] = (u32)(sbase + (ROW)); \
      ++scW; full = (scW >= Kcap); \
    }
#define SWEEPG(G, RWG) \
    if (!full && (((G) << 6) < RL)) { \
      const int rb = (G) << 6; \
      LD4(a00,a01,a02,a03, rb+0) LD4(a10,a11,a12,a13, rb+1) \
      LD4(a20,a21,a22,a23, rb+2) LD4(a30,a31,a32,a33, rb+3) \
      for (int bb = 0; bb < 64 && !full; bb += 4) { \
        LD4(b00,b01,b02,b03, rb+bb+4) LD4(b10,b11,b12,b13, rb+bb+5) \
        LD4(b20,b21,b22,b23, rb+bb+6) LD4(b30,b31,b32,b33, rb+bb+7) \
        PRX(RWG, bb+0, a00,a01,a02,a03, rb+bb+0) \
        PRX(RWG, bb+1, a10,a11,a12,a13, rb+bb+1) \
        PRX(RWG, bb+2, a20,a21,a22,a23, rb+bb+2) \
        PRX(RWG, bb+3, a30,a31,a32,a33, rb+bb+3) \
        a00=b00;a01=b01;a02=b02;a03=b03; a10=b10;a11=b11;a12=b12;a13=b13; \
        a20=b20;a21=b21;a22=b22;a23=b23; a30=b30;a31=b31;a32=b32;a33=b33; \
      } \
    }
    SWEEPG(0, rw0) SWEEPG(1, rw1) SWEEPG(2, rw2) SWEEPG(3, rw3)
#undef SWEEPG
#undef PRX
#undef LD4
    if (lane == 0) scLds = scW;
  };

  // ================= selection-window loop (1 window typical) =============
  while (sc < Kcap && processed < nv) {
    int rem = nv - processed;
    int need = (rem < RSEL) ? rem : RSEL;

    // ---- 2-level histogram threshold select (exact, prefix-closed) ----
    if (tid < 256) { hist1[tid] = 0; hist2[tid] = 0; }
    if (tid == 0) cSelSh = 0;
    __syncthreads();
    bool val0 = (kq0 > minKey) && ((u32)(kq0 >> 32) < INVH);
    bool val1 = (kq1 > minKey) && ((u32)(kq1 >> 32) < INVH);
    if (val0) atomicAdd(&hist1[(int)((kq0 >> 56) & 255)], 1);
    if (val1) atomicAdd(&hist1[(int)((kq1 >> 56) & 255)], 1);
    __syncthreads();
    if (wid == 0) bucket_select(hist1, need, lane, &selB1, &selC1);
    __syncthreads();
    const int B1 = selB1, C1 = selC1;
    if (val0 && (int)((kq0 >> 56) & 255) == B1)
      atomicAdd(&hist2[(int)((kq0 >> 48) & 255)], 1);
    if (val1 && (int)((kq1 >> 56) & 255) == B1)
      atomicAdd(&hist2[(int)((kq1 >> 48) & 255)], 1);
    __syncthreads();
    if (wid == 0) bucket_select(hist2, need - C1, lane, &selB2, &selD2);
    __syncthreads();
    const int pred16 = (selB1 << 8) | selB2;

    // ---- compact selected keys (order irrelevant; sorted next) ----
    bool s0 = val0 && (int)((kq0 >> 48) & 0xFFFF) <= pred16;
    bool s1 = val1 && (int)((kq1 >> 48) & 0xFFFF) <= pred16;
    {
      u64 b0 = __ballot(s0), b1 = __ballot(s1);
      int cnt = __popcll(b0) + __popcll(b1);
      int basePos = 0;
      if (lane == 0) basePos = cnt ? atomicAdd(&cSelSh, cnt) : 0;
      basePos = __shfl(basePos, 0);
      u64 lm = (1ULL << lane) - 1ULL;
      int p0 = basePos + __popcll(b0 & lm);
      int p1 = basePos + __popcll(b0) + __popcll(b1 & lm);
      if (s0 && p0 < SCAP) mbAu[p0] = kq0;
      if (s1 && p1 < SCAP) mbAu[p1] = kq1;
    }
    __syncthreads();
    int Csel = cSelSh; if (Csel > SCAP) Csel = SCAP;  // clamp (float-continuous
                                                      // scores: never overflows)
    if (tid < SCAP && tid >= Csel) mbAu[tid] = ~0ULL;
    __syncthreads();

    // ---- bitonic sort 512 (threads<512 hold 1 element; pad sorts last) ----
    u64 key = (tid < SCAP) ? mbAu[tid] : ~0ULL;
    int parity = 0;
    auto ldsp = [&](int k, int j) {
      u64* buf = parity ? mbBu : mbAu; parity ^= 1;
      if (tid < SCAP) buf[tid] = key;
      __syncthreads();
      if (tid < SCAP) { u64 o = buf[tid ^ j]; cmpex64(key, o, tid, j, k); }
    };
    auto shfp = [&](int k, int j) {
      if (tid < SCAP) { u64 o = shflx_u64(key, j); cmpex64(key, o, tid, j, k); }
    };
    for (int k = 2; k <= 64; k <<= 1)
      for (int j = k >> 1; j >= 1; j >>= 1) shfp(k, j);
    ldsp(128, 64);
    for (int j = 32; j >= 1; j >>= 1) shfp(128, j);
    ldsp(256, 128); ldsp(256, 64);
    for (int j = 32; j >= 1; j >>= 1) shfp(256, j);
    ldsp(512, 256); ldsp(512, 128); ldsp(512, 64);
    for (int j = 32; j >= 1; j >>= 1) shfp(512, j);
    if (tid < SCAP) skeyW64[tid] = key;
    __syncthreads();

    const int RL1 = (Csel < SBLK) ? Csel : SBLK;
    const int RL2 = Csel - RL1;                 // 0..256

    // ---- gather BOTH stages' boxes + stage-1 colkill (thread-local) ----
    if (tid < SBLK) {
      int p = tid; if (p > Csel - 1) p = Csel - 1;
      u64 kq = skeyW64[p];
      float4 b = decoded[(u32)kq];
      bx0[tid] = b.x; by0[tid] = b.y; bx1[tid] = b.z; by1[tid] = b.w;
      float ab = __fmul_rn(__fsub_rn(b.z, b.x), __fsub_rn(b.w, b.y));
      areaA[tid] = ab;
      // colkill vs prior-window survivors (sc==0 on window 1 -> no-op)
      bool kill = false;
      for (int u = 0; u < sc; ++u) {
        float ix0 = sx0[u], iy0 = sy0[u], ix1 = sx1[u], iy1 = sy1[u];
        float ia = sarea[u];
        float lx = fmaxf(ix0, b.x), ly = fmaxf(iy0, b.y);
        float rx = fminf(ix1, b.z), ry = fminf(iy1, b.w);
        float w_ = fmaxf(__fsub_rn(rx, lx), 0.0f);
        float h_ = fmaxf(__fsub_rn(ry, ly), 0.0f);
        float inter = __fmul_rn(w_, h_);
        float iou = __fdiv_rn(inter, __fsub_rn(__fadd_rn(ia, ab), inter));
        kill = kill || (iou > ovr);
      }
      u64 bal = __ballot(kill);
      if (lane == 0) remInitW[wid] = bal;       // wid 0..3, always defined
    } else if (tid < 2 * SBLK && RL2 > 0) {
      int p = tid; if (p > Csel - 1) p = Csel - 1;
      u64 kq = skeyW64[p];
      float4 b = decoded[(u32)kq];
      int t2 = tid - SBLK;
      bx0B[t2] = b.x; by0B[t2] = b.y; bx1B[t2] = b.z; by1B[t2] = b.w;
      areaB[t2] = __fmul_rn(__fsub_rn(b.z, b.x), __fsub_rn(b.w, b.y));
    }
    __syncthreads();

    // ---- stage-1 mask build (all 16 waves; skip colkilled rows) ----
    {
      int nw = (RL1 + 63) >> 6;
      for (int r2 = wid; r2 < RL1; r2 += 16) {
        if ((remInitW[r2 >> 6] >> (r2 & 63)) & 1ULL) continue;
        float ix0 = bx0[r2], iy0 = by0[r2], ix1 = bx1[r2], iy1 = by1[r2];
        float ia = areaA[r2];
        for (int ct = (r2 >> 6); ct < nw; ++ct) {
          int j = (ct << 6) + lane;
          float jx0 = bx0[j], jy0 = by0[j], jx1 = bx1[j], jy1 = by1[j];
          float ab = areaA[j];
          float lx = fmaxf(ix0, jx0), ly = fmaxf(iy0, jy0);
          float rx = fminf(ix1, jx1), ry = fminf(iy1, jy1);
          float w_ = fmaxf(__fsub_rn(rx, lx), 0.0f);
          float h_ = fmaxf(__fsub_rn(ry, ly), 0.0f);
          float inter = __fmul_rn(w_, h_);
          float iou = __fdiv_rn(inter, __fsub_rn(__fadd_rn(ia, ab), inter));
          bool bit = iou > ovr;
          if (ct == (r2 >> 6)) bit = bit && (j > r2);
          u64 bal = __ballot(bit);
          if (lane == 0) maskW[(r2 << 2) + ct] = bal;
        }
      }
    }
    __syncthreads();

    // ---- OVERLAP: wave 0 sweeps stage 1; waves 1-15 build stage-2 masks ---
    if (wid == 0) {
      sweep(maskW, RL1, 0);
    } else if (RL2 > 0) {
      int nw2 = (RL2 + 63) >> 6;
      for (int r2 = wid - 1; r2 < RL2; r2 += 15) {
        float ix0 = bx0B[r2], iy0 = by0B[r2], ix1 = bx1B[r2], iy1 = by1B[r2];
        float ia = areaB[r2];
        for (int ct = (r2 >> 6); ct < nw2; ++ct) {
          int j = (ct << 6) + lane;
          float jx0 = bx0B[j], jy0 = by0B[j], jx1 = bx1B[j], jy1 = by1B[j];
          float ab = areaB[j];
          float lx = fmaxf(ix0, jx0), ly = fmaxf(iy0, jy0);
          float rx = fminf(ix1, jx1), ry = fminf(iy1, jy1);
          float w_ = fmaxf(__fsub_rn(rx, lx), 0.0f);
          float h_ = fmaxf(__fsub_rn(ry, ly), 0.0f);
          float inter = __fmul_rn(w_, h_);
          float iou = __fdiv_rn(inter, __fsub_rn(__fadd_rn(ia, ab), inter));
          bool bit = iou > ovr;
          if (ct == (r2 >> 6)) bit = bit && (j > r2);
          u64 bal = __ballot(bit);
          if (lane == 0) maskWB[(r2 << 2) + ct] = bal;
        }
      }
    }
    __syncthreads();

    // ---- fill stage-1 survivors (parallel) ----
    {
      int scNew = scLds;
      if (tid >= sc && tid < scNew) {
        int wrow = (int)survRows[tid];            // in [0, RL1)
        sx0[tid] = bx0[wrow]; sy0[tid] = by0[wrow];
        sx1[tid] = bx1[wrow]; sy1[tid] = by1[wrow];
        sarea[tid] = areaA[wrow];
        survKeyH[tid] = (u32)(skeyW64[wrow] >> 32);
      }
      __syncthreads();
      sc = scNew;
    }

    // ---- stage 2 (mask already built speculatively) ----
    if (sc < Kcap && RL2 > 0) {
      // colkill stage-2 cols vs ALL survivors so far (thread-local)
      if (tid < SBLK) {
        bool kill = false;
        if (tid < RL2) {
          float jx0 = bx0B[tid], jy0 = by0B[tid];
          float jx1 = bx1B[tid], jy1 = by1B[tid];
          float ab = areaB[tid];
          for (int u = 0; u < sc; ++u) {
            float ix0 = sx0[u], iy0 = sy0[u], ix1 = sx1[u], iy1 = sy1[u];
            float ia = sarea[u];
            float lx = fmaxf(ix0, jx0), ly = fmaxf(iy0, jy0);
            float rx = fminf(ix1, jx1), ry = fminf(iy1, jy1);
            float w_ = fmaxf(__fsub_rn(rx, lx), 0.0f);
            float h_ = fmaxf(__fsub_rn(ry, ly), 0.0f);
            float inter = __fmul_rn(w_, h_);
            float iou = __fdiv_rn(inter, __fsub_rn(__fadd_rn(ia, ab), inter));
            kill = kill || (iou > ovr);
          }
        }
        u64 bal = __ballot(kill);
        if (lane == 0) remInitW[wid] = bal;
      }
      __syncthreads();
      if (wid == 0) sweep(maskWB, RL2, SBLK);
      __syncthreads();
      {
        int scNew = scLds;
        if (tid >= sc && tid < scNew) {
          int wrow = (int)survRows[tid];          // in [SBLK, SBLK+RL2)
          int rr = wrow - SBLK;
          sx0[tid] = bx0B[rr]; sy0[tid] = by0B[rr];
          sx1[tid] = bx1B[rr]; sy1[tid] = by1B[rr];
          sarea[tid] = areaB[rr];
          survKeyH[tid] = (u32)(skeyW64[wrow] >> 32);
        }
        __syncthreads();
        sc = scNew;
      }
    }

    minKey = skeyW64[Csel - 1];   // largest processed key (uniform read)
    processed += Csel;
    __syncthreads();
  }

  // ---- emit per-class survivor list (greedy order) ----
  if (tid < CPAD) {
    int o = cls * CPAD + tid;
    if (tid < sc) {
      cand[o] = ((u64)survKeyH[tid] << 32) | (u32)o;  // low32 == tie-order
      cbox[o] = make_float4(sx0[tid], sy0[tid], sx1[tid], sy1[tid]);
    } else {
      cand[o] = ~0ULL;
    }
  }

  // ---- signal completion; last block does the global top-K ----
  __threadfence();
  __syncthreads();
  if (tid == 0) lastSh = atomicAdd(done, 1u);
  __syncthreads();
  if (lastSh != NFG - 1) return;
  __threadfence();

  u64* kk = (u64*)LDSW;            // overlay (sort/mask regions dead)
  u64* ck = (u64*)(LDSW + 5120);   // overlay stage SoA (dead)
  if (tid == 0) cCnt = 0;
  if (tid < 256) { hist1[tid] = 0; hist2[tid] = 0; }
  __syncthreads();
  for (int t = tid; t < CTOT; t += NTHR) {
    u64 v = cand[t];
    kk[t] = v;
    if (v != ~0ULL) atomicAdd(&hist1[(int)(v >> 56)], 1);
  }
  __syncthreads();
  if (wid == 0) {                  // M = total valid count (wave reduce)
    int b4 = lane << 2;
    int s = hist1[b4] + hist1[b4 + 1] + hist1[b4 + 2] + hist1[b4 + 3];
    #pragma unroll
    for (int off = 32; off; off >>= 1) s += __shfl_xor(s, off);
    if (lane == 0) mSh = s;
  }
  __syncthreads();
  const int M = mSh;
  const int Kneed = (K < M) ? K : M;

  if (Kneed > 0) {
    if (wid == 0) bucket_select(hist1, Kneed, lane, &selB1, &selC1);
    __syncthreads();
    const int B1 = selB1, C1 = selC1;
    for (int t = tid; t < CTOT; t += NTHR) {
      u64 v = kk[t];
      if (v != ~0ULL && (int)(v >> 56) == B1)
        atomicAdd(&hist2[(int)((v >> 48) & 255)], 1);
    }
    __syncthreads();
    if (wid == 0) bucket_select(hist2, Kneed - C1, lane, &selB2, &selD2);
    __syncthreads();
    const int B2 = selB2;
    for (int t = tid; t < CTOT; t += NTHR) {   // compact contenders
      u64 v = kk[t];
      if (v == ~0ULL) continue;
      int b1 = (int)(v >> 56);
      int b2 = (int)((v >> 48) & 255);
      if (b1 < B1 || (b1 == B1 && b2 <= B2)) {
        int pos = atomicAdd(&cCnt, 1);
        if (pos < CSEL) ck[pos] = v;
      }
    }
    __syncthreads();
    const int C = cCnt;
    if (C <= CSEL) {
      // contender set downward-closed -> in-set rank == global rank
      if (tid < C) {
        u64 my = ck[tid];
        int rank = 0;
        for (int u = 0; u < C; ++u) rank += (ck[u] < my) ? 1 : 0;
        if (rank < K) {
          u32 flat = (u32)(my & 0xFFFFFFFFu);
          float score = key_to_float((u32)(my >> 32));
          int c2 = (int)(flat >> 7);
          float4 b = cbox[flat];
          out[rank * 4 + 0] = b.x;
          out[rank * 4 + 1] = b.y;
          out[rank * 4 + 2] = b.z;
          out[rank * 4 + 3] = b.w;
          out[K * 4 + rank] = (float)(c2 + 1);
          out[K * 5 + rank] = score;
        }
      }
    } else {
      // fallback: exact rank via 20 per-class binary searches
      for (int t = tid; t < CTOT; t += NTHR) {
        u64 kap = kk[t];
        if (kap == ~0ULL) continue;
        int rank = 0;
        #pragma unroll
        for (int cc2 = 0; cc2 < NFG; ++cc2) {
          const u64* a = kk + cc2 * CPAD;
          int lb = 0;
          #pragma unroll
          for (int s2 = CPAD >> 1; s2; s2 >>= 1) {
            int pq = lb + s2;
            if (a[pq - 1] < kap) lb = pq;
          }
          rank += lb;
        }
        if (rank < K) {
          u32 flat = (u32)(kap & 0xFFFFFFFFu);
          float score = key_to_float((u32)(kap >> 32));
          int c2 = (int)(flat >> 7);
          float4 b = cbox[flat];
          out[rank * 4 + 0] = b.x;
          out[rank * 4 + 1] = b.y;
          out[rank * 4 + 2] = b.z;
          out[rank * 4 + 3] = b.w;
          out[K * 4 + rank] = (float)(c2 + 1);
          out[K * 5 + rank] = score;
        }
      }
    }
  }
  __syncthreads();
  for (int r = tid; r < K; r += NTHR) {
    if (r >= M) {
      out[r * 4 + 0] = 0.0f; out[r * 4 + 1] = 0.0f;
      out[r * 4 + 2] = 1.0f; out[r * 4 + 3] = 1.0f;
      out[K * 4 + r] = 0.0f;
      out[K * 5 + r] = 0.0f;
    }
  }
}

// ---- launch ---------------------------------------------------------------
extern "C" void kernel_launch(void* const* d_in, const int* in_sizes, int n_in,
                              void* d_out, int out_size, void* d_ws, size_t ws_size,
                              hipStream_t stream) {
  const float* rois        = (const float*)d_in[0];
  const float* locs        = (const float*)d_in[1];
  const float* scores      = (const float*)d_in[2];
  const float* min_score   = (const float*)d_in[3];
  const float* max_overlap = (const float*)d_in[4];
  const int*   top_k       = (const int*)d_in[5];

  char* ws = (char*)d_ws;
  // layout: cand 2560*8 | cbox 2560*16 | probsT 20*2048*4 | decoded 2048*16 | done 4
  u64*    cand    = (u64*)ws;
  float4* cbox    = (float4*)(ws + 20480);
  float*  probsT  = (float*)(ws + 20480 + 40960);
  float4* decoded = (float4*)(ws + 20480 + 40960 + 163840);
  u32*    done    = (u32*)(ws + 20480 + 40960 + 163840 + 32768);

  k_decode<<<NROI / DROWS, 64, 0, stream>>>(rois, locs, scores, probsT, decoded, done);
  k_nms<<<NFG, NTHR, 0, stream>>>(probsT, decoded, min_score, max_overlap,
                                  cand, cbox, done, (float*)d_out, top_k);
}

// Round 16
// 57.224 us; speedup vs baseline: 1.0418x; 1.0418x over previous
//
#include <hip/hip_runtime.h>
#include <cstdint>

#define NROI 2048
#define NCLS 21
#define NFG  20
#define CPAD 128          // survivor slots per class (>= top_k=100)
#define CTOT (NFG * CPAD) // 2560
#define NTHR 512          // threads per NMS block (8 waves)
#define SBLK 256          // rows per NMS stage
#define RSEL 480          // selection rank target per window
#define SCAP 512          // selection capacity (sorted window size)
#define CSEL 512          // contender cap for top-k rank-count
#define DROWS 64          // rows per decode block
#define INVH 0xFF800000u  // desc_key(-inf) == invalid marker

typedef unsigned long long u64;
typedef unsigned int u32;

// ---- sortable key helpers -------------------------------------------------
// desc_key(s): larger float -> smaller uint, so ascending sort on
// u64 key = (desc_key(score)<<32)|index == (score desc, index asc).
__device__ __forceinline__ u32 desc_key(float s) {
  u32 u = __float_as_uint(s);
  u32 asc = (u & 0x80000000u) ? ~u : (u | 0x80000000u);
  return ~asc;
}
__device__ __forceinline__ float key_to_float(u32 desc) {
  u32 asc = ~desc;
  u32 u = (asc & 0x80000000u) ? (asc ^ 0x80000000u) : ~asc;
  return __uint_as_float(u);
}
__device__ __forceinline__ u64 shflx_u64(u64 v, int m) {
  u32 lo = (u32)v, hi = (u32)(v >> 32);
  lo = (u32)__shfl_xor((int)lo, m);
  hi = (u32)__shfl_xor((int)hi, m);
  return ((u64)hi << 32) | (u64)lo;
}
// bitonic compare-exchange for element i at pass (k, j), u64 lex order
__device__ __forceinline__ void cmpex64(u64& mine, u64 other, int i, int j, int k) {
  bool amIlow = ((i & j) == 0);
  bool dir = ((i & k) == 0);
  bool otherLess = other < mine;
  if (otherLess != (amIlow != dir)) mine = other;
}

// wave-0 parallel 256-bin bucket select: smallest bucket b with
// cum(h[0..b]) >= need; *outC = cum before b. (1 <= need <= total)
__device__ __forceinline__ void bucket_select(const int* h, int need, int lane,
                                              int* outB, int* outC) {
  int base = lane << 2;
  int c0 = h[base], c1 = h[base + 1], c2 = h[base + 2], c3 = h[base + 3];
  int s = c0 + c1 + c2 + c3;
  int pre = s;
  #pragma unroll
  for (int off = 1; off < 64; off <<= 1) {
    int v = __shfl_up(pre, off);
    if (lane >= off) pre += v;
  }
  u64 ball = __ballot(pre >= need);
  int ln = __ffsll((long long)ball) - 1;
  int exc = __shfl(pre, ln) - __shfl(s, ln);
  int b0 = __shfl(c0, ln), b1 = __shfl(c1, ln), b2 = __shfl(c2, ln);
  int bkt, cb;
  if (exc + b0 >= need)                { bkt = (ln << 2) + 0; cb = exc; }
  else if (exc + b0 + b1 >= need)      { bkt = (ln << 2) + 1; cb = exc + b0; }
  else if (exc + b0 + b1 + b2 >= need) { bkt = (ln << 2) + 2; cb = exc + b0 + b1; }
  else                                 { bkt = (ln << 2) + 3; cb = exc + b0 + b1 + b2; }
  if (lane == 0) { *outB = bkt; *outC = cb; }
}

// ---- phase 1: coalesced softmax + argmax + decode (32 blocks x 64 thr) ----
__global__ __launch_bounds__(64)
void k_decode(const float* __restrict__ rois,
              const float* __restrict__ locs,
              const float* __restrict__ scores,
              float* __restrict__ probsT,     // [NFG][NROI]: class c+1 -> row c
              float4* __restrict__ decoded,
              u32* __restrict__ done) {
  __shared__ float srow[DROWS][NCLS + 2];   // stride 23 (odd) -> conflict-free
  const int tid = threadIdx.x;
  const int rbase = blockIdx.x * DROWS;
  if (rbase == 0 && tid == 0) *done = 0u;   // reset last-block counter each launch

  const float* src = scores + (size_t)rbase * NCLS;
  for (int t = tid; t < DROWS * NCLS; t += 64)
    srow[t / NCLS][t % NCLS] = src[t];
  __syncthreads();

  const int r = rbase + tid;
  float s[NCLS];
  #pragma unroll
  for (int c = 0; c < NCLS; ++c) s[c] = srow[tid][c];
  float m = s[0];
  #pragma unroll
  for (int c = 0; c < NCLS; ++c) m = fmaxf(m, s[c]);
  float sum = 0.0f;
  #pragma unroll
  for (int c = 0; c < NCLS; ++c) { s[c] = expf(s[c] - m); sum += s[c]; }

  float pb = s[0] / sum; int best = 0;
  #pragma unroll
  for (int c = 1; c < NCLS; ++c) {
    float p = s[c] / sum;
    probsT[(c - 1) * NROI + r] = p;        // coalesced store per class
    if (p > pb) { pb = p; best = c; }      // strict > == first-index argmax
  }

  float4 roi = ((const float4*)rois)[r];
  float pcx = __fmul_rn(__fadd_rn(roi.x, roi.z), 0.5f);
  float pcy = __fmul_rn(__fadd_rn(roi.y, roi.w), 0.5f);
  float pw  = __fsub_rn(roi.z, roi.x);
  float ph  = __fsub_rn(roi.w, roi.y);

  float4 gl = ((const float4*)locs)[r * NCLS + best];   // 16B-aligned
  float g0 = gl.x / 10.0f;
  float g1 = gl.y / 10.0f;
  float g2 = gl.z / 20.0f;
  float g3 = gl.w / 20.0f;

  // no-FMA-contraction decode to match numpy rounding
  float cx = __fadd_rn(__fmul_rn(g0, pw), pcx);
  float cy = __fadd_rn(__fmul_rn(g1, ph), pcy);
  float w  = __fmul_rn(expf(g2), pw);
  float h  = __fmul_rn(expf(g3), ph);
  float hw = __fmul_rn(w, 0.5f);
  float hh = __fmul_rn(h, 0.5f);
  decoded[r] = make_float4(__fsub_rn(cx, hw), __fsub_rn(cy, hh),
                           __fadd_rn(cx, hw), __fadd_rn(cy, hh));
}

// ---- phase 2: select+sort window -> staged bitmask NMS -> last-block topk -
__global__ __launch_bounds__(NTHR)
void k_nms(const float* __restrict__ probsT,
           const float4* __restrict__ decoded,
           const float* __restrict__ min_score_p,
           const float* __restrict__ max_overlap_p,
           u64* __restrict__ cand,
           float4* __restrict__ cbox,
           u32* __restrict__ done,
           float* __restrict__ out,
           const int* __restrict__ top_k_p) {
  // LDS word map (u32), ~29 KB total:
  //  [0,1024)     mbA u64[512]        (sort mailbox A; tail: kk[0..])
  //  [1024,2048)  mbB u64[512]        (sort mailbox B)
  //  [2048,3072)  skeyW u64[512]      (sorted window keys)
  //  [3072,5120)  maskW u64[256*4]
  //  [5120,6400)  stage SoA bx0/by0/bx1/by1/areaA [256] each   (tail: ck@5120)
  //  [6400,7040)  surv SoA sx0/sy0/sx1/sy1/sarea [128] each
  //  [7040,7168)  survKeyH[128]
  //  [7168,7296)  survRows[128]
  __shared__ u32 LDSW[7296];
  __shared__ u64 remInitW[4];
  __shared__ int hist1[256], hist2[256];
  __shared__ int cntLds, scLds, cSelSh, selB1, selC1, selB2, selD2, mSh, cCnt;
  __shared__ u32 lastSh;

  u64* mbAu    = (u64*)(LDSW + 0);
  u64* mbBu    = (u64*)(LDSW + 1024);
  u64* skeyW64 = (u64*)(LDSW + 2048);
  u64* maskW   = (u64*)(LDSW + 3072);
  float* bx0   = (float*)(LDSW + 5120);
  float* by0   = (float*)(LDSW + 5376);
  float* bx1   = (float*)(LDSW + 5632);
  float* by1   = (float*)(LDSW + 5888);
  float* areaA = (float*)(LDSW + 6144);
  float* sx0   = (float*)(LDSW + 6400);
  float* sy0   = (float*)(LDSW + 6528);
  float* sx1   = (float*)(LDSW + 6656);
  float* sy1   = (float*)(LDSW + 6784);
  float* sarea = (float*)(LDSW + 6912);
  u32* survKeyH = LDSW + 7040;
  u32* survRows = LDSW + 7168;

  const int cls = blockIdx.x;
  const int tid = threadIdx.x;
  const int lane = tid & 63;
  const int wid = tid >> 6;
  const float msc = *min_score_p;
  const float ovr = *max_overlap_p;
  const int K = *top_k_p;
  const int Kcap = (K < CPAD) ? K : CPAD;

  if (tid == 0) { cntLds = 0; scLds = 0; }
  __syncthreads();

  // ---- per-thread keys (4 rows each) + valid count ----
  float pA = probsT[cls * NROI + tid];
  float pB = probsT[cls * NROI + tid + 512];
  float pC = probsT[cls * NROI + tid + 1024];
  float pD = probsT[cls * NROI + tid + 1536];
  bool vA = pA > msc, vB = pB > msc, vC = pC > msc, vD = pD > msc;
  u64 kqA = ((u64)desc_key(vA ? pA : -__builtin_inff()) << 32) | (u32)tid;
  u64 kqB = ((u64)desc_key(vB ? pB : -__builtin_inff()) << 32) | (u32)(tid + 512);
  u64 kqC = ((u64)desc_key(vC ? pC : -__builtin_inff()) << 32) | (u32)(tid + 1024);
  u64 kqD = ((u64)desc_key(vD ? pD : -__builtin_inff()) << 32) | (u32)(tid + 1536);
  {
    u64 ba = __ballot(vA), bb = __ballot(vB);
    u64 bc = __ballot(vC), bd = __ballot(vD);
    if (lane == 0)
      atomicAdd(&cntLds, __popcll(ba) + __popcll(bb) + __popcll(bc) + __popcll(bd));
  }
  __syncthreads();
  const int nv = cntLds;

  int sc = 0;
  int processed = 0;
  u64 minKey = 0ULL;   // exclusive lower bound of already-processed keys

  // ================= selection-window loop (1 window typical) =============
  while (sc < Kcap && processed < nv) {
    int rem = nv - processed;
    int need = (rem < RSEL) ? rem : RSEL;

    // ---- 2-level histogram threshold select (exact, prefix-closed) ----
    if (tid < 256) { hist1[tid] = 0; hist2[tid] = 0; }
    if (tid == 0) cSelSh = 0;
    __syncthreads();
    bool valA = (kqA > minKey) && ((u32)(kqA >> 32) < INVH);
    bool valB = (kqB > minKey) && ((u32)(kqB >> 32) < INVH);
    bool valC = (kqC > minKey) && ((u32)(kqC >> 32) < INVH);
    bool valD = (kqD > minKey) && ((u32)(kqD >> 32) < INVH);
    if (valA) atomicAdd(&hist1[(int)((kqA >> 56) & 255)], 1);
    if (valB) atomicAdd(&hist1[(int)((kqB >> 56) & 255)], 1);
    if (valC) atomicAdd(&hist1[(int)((kqC >> 56) & 255)], 1);
    if (valD) atomicAdd(&hist1[(int)((kqD >> 56) & 255)], 1);
    __syncthreads();
    if (wid == 0) bucket_select(hist1, need, lane, &selB1, &selC1);
    __syncthreads();
    const int B1 = selB1, C1 = selC1;
    if (valA && (int)((kqA >> 56) & 255) == B1)
      atomicAdd(&hist2[(int)((kqA >> 48) & 255)], 1);
    if (valB && (int)((kqB >> 56) & 255) == B1)
      atomicAdd(&hist2[(int)((kqB >> 48) & 255)], 1);
    if (valC && (int)((kqC >> 56) & 255) == B1)
      atomicAdd(&hist2[(int)((kqC >> 48) & 255)], 1);
    if (valD && (int)((kqD >> 56) & 255) == B1)
      atomicAdd(&hist2[(int)((kqD >> 48) & 255)], 1);
    __syncthreads();
    if (wid == 0) bucket_select(hist2, need - C1, lane, &selB2, &selD2);
    __syncthreads();
    const int pred16 = (selB1 << 8) | selB2;

    // ---- compact selected keys (order irrelevant; sorted next) ----
    bool sA = valA && (int)((kqA >> 48) & 0xFFFF) <= pred16;
    bool sB = valB && (int)((kqB >> 48) & 0xFFFF) <= pred16;
    bool sC = valC && (int)((kqC >> 48) & 0xFFFF) <= pred16;
    bool sD = valD && (int)((kqD >> 48) & 0xFFFF) <= pred16;
    {
      u64 bA = __ballot(sA), bB = __ballot(sB);
      u64 bC = __ballot(sC), bD = __ballot(sD);
      int cnt = __popcll(bA) + __popcll(bB) + __popcll(bC) + __popcll(bD);
      int basePos = 0;
      if (lane == 0) basePos = cnt ? atomicAdd(&cSelSh, cnt) : 0;
      basePos = __shfl(basePos, 0);
      u64 lm = (1ULL << lane) - 1ULL;
      int pA_ = basePos + __popcll(bA & lm);
      int pB_ = basePos + __popcll(bA) + __popcll(bB & lm);
      int pC_ = basePos + __popcll(bA) + __popcll(bB) + __popcll(bC & lm);
      int pD_ = basePos + __popcll(bA) + __popcll(bB) + __popcll(bC) + __popcll(bD & lm);
      if (sA && pA_ < SCAP) mbAu[pA_] = kqA;
      if (sB && pB_ < SCAP) mbAu[pB_] = kqB;
      if (sC && pC_ < SCAP) mbAu[pC_] = kqC;
      if (sD && pD_ < SCAP) mbAu[pD_] = kqD;
    }
    __syncthreads();
    int Csel = cSelSh; if (Csel > SCAP) Csel = SCAP;  // clamp (float-continuous
                                                      // scores: never overflows)
    if (tid >= Csel) mbAu[tid] = ~0ULL;               // NTHR==SCAP: full cover
    __syncthreads();

    // ---- bitonic sort 512 (exactly 1 element per thread; pad sorts last) --
    u64 key = mbAu[tid];
    int parity = 0;
    auto ldsp = [&](int k, int j) {
      u64* buf = parity ? mbBu : mbAu; parity ^= 1;
      buf[tid] = key;
      __syncthreads();
      u64 o = buf[tid ^ j];
      cmpex64(key, o, tid, j, k);
    };
    auto shfp = [&](int k, int j) {
      u64 o = shflx_u64(key, j);
      cmpex64(key, o, tid, j, k);
    };
    for (int k = 2; k <= 64; k <<= 1)
      for (int j = k >> 1; j >= 1; j >>= 1) shfp(k, j);
    ldsp(128, 64);
    for (int j = 32; j >= 1; j >>= 1) shfp(128, j);
    ldsp(256, 128); ldsp(256, 64);
    for (int j = 32; j >= 1; j >>= 1) shfp(256, j);
    ldsp(512, 256); ldsp(512, 128); ldsp(512, 64);
    for (int j = 32; j >= 1; j >>= 1) shfp(512, j);
    skeyW64[tid] = key;
    __syncthreads();

    // ---- staged greedy NMS over this window's Csel sorted rows ----
    for (int base = 0; base < Csel && sc < Kcap; base += SBLK) {
      int RL = Csel - base; if (RL > SBLK) RL = SBLK;
      // gather stage boxes
      if (tid < SBLK) {
        int p = base + tid; if (p > Csel - 1) p = Csel - 1;
        u64 kq = skeyW64[p];
        float4 b = decoded[(u32)kq];
        bx0[tid] = b.x; by0[tid] = b.y; bx1[tid] = b.z; by1[tid] = b.w;
        areaA[tid] = __fmul_rn(__fsub_rn(b.z, b.x), __fsub_rn(b.w, b.y));
      }
      if (tid < 4) remInitW[tid] = 0ULL;
      __syncthreads();

      // column-kill vs all existing survivors (waves 0-3)
      if (sc > 0 && tid < SBLK) {
        float jx0 = bx0[tid], jy0 = by0[tid], jx1 = bx1[tid], jy1 = by1[tid];
        float ab = areaA[tid];
        bool kill = false;
        for (int u = 0; u < sc; ++u) {
          float ix0 = sx0[u], iy0 = sy0[u], ix1 = sx1[u], iy1 = sy1[u];
          float ia = sarea[u];
          float lx = fmaxf(ix0, jx0), ly = fmaxf(iy0, jy0);
          float rx = fminf(ix1, jx1), ry = fminf(iy1, jy1);
          float w_ = fmaxf(__fsub_rn(rx, lx), 0.0f);
          float h_ = fmaxf(__fsub_rn(ry, ly), 0.0f);
          float inter = __fmul_rn(w_, h_);
          float iou = __fdiv_rn(inter, __fsub_rn(__fadd_rn(ia, ab), inter));
          kill = kill || (iou > ovr);
        }
        u64 bal = __ballot(kill);
        if (lane == 0) remInitW[wid] = bal;
      }
      __syncthreads();   // publish remInitW so mask build can skip dead rows

      // build upper-triangle suppression bit matrix (dead rows skipped:
      // a dead row's mask is never OR'd by the sweep)
      {
        int nw = (RL + 63) >> 6;
        for (int r2 = wid; r2 < RL; r2 += 8) {
          if ((remInitW[r2 >> 6] >> (r2 & 63)) & 1ULL) continue;
          float ix0 = bx0[r2], iy0 = by0[r2], ix1 = bx1[r2], iy1 = by1[r2];
          float ia = areaA[r2];
          for (int ct = (r2 >> 6); ct < nw; ++ct) {
            int j = (ct << 6) + lane;
            float jx0 = bx0[j], jy0 = by0[j], jx1 = bx1[j], jy1 = by1[j];
            float ab = areaA[j];
            float lx = fmaxf(ix0, jx0), ly = fmaxf(iy0, jy0);
            float rx = fminf(ix1, jx1), ry = fminf(iy1, jy1);
            float w_ = fmaxf(__fsub_rn(rx, lx), 0.0f);
            float h_ = fmaxf(__fsub_rn(ry, ly), 0.0f);
            float inter = __fmul_rn(w_, h_);
            float iou = __fdiv_rn(inter, __fsub_rn(__fadd_rn(ia, ab), inter));
            bool bit = iou > ovr;
            if (ct == (r2 >> 6)) bit = bit && (j > r2);
            u64 bal = __ballot(bit);
            if (lane == 0) maskW[(r2 << 2) + ct] = bal;
          }
        }
      }
      __syncthreads();

      // ---- sweep: linear scan, 4-row register prefetch (no dependent
      //      loads; per-row cost = bit test + 4 ORs) ----
      if (wid == 0) {
        int t0 = RL;
        u64 rw0 = (t0 <= 0) ? ~0ULL : ((t0 >= 64) ? 0ULL : (~0ULL << t0));
        int t1 = t0 - 64;
        u64 rw1 = (t1 <= 0) ? ~0ULL : ((t1 >= 64) ? 0ULL : (~0ULL << t1));
        int t2 = t0 - 128;
        u64 rw2 = (t2 <= 0) ? ~0ULL : ((t2 >= 64) ? 0ULL : (~0ULL << t2));
        int t3 = t0 - 192;
        u64 rw3 = (t3 <= 0) ? ~0ULL : ((t3 >= 64) ? 0ULL : (~0ULL << t3));
        rw0 |= remInitW[0]; rw1 |= remInitW[1];
        rw2 |= remInitW[2]; rw3 |= remInitW[3];
        int scW = sc;
        bool full = scW >= Kcap;
        u64 a00,a01,a02,a03,a10,a11,a12,a13,a20,a21,a22,a23,a30,a31,a32,a33;
        u64 b00,b01,b02,b03,b10,b11,b12,b13,b20,b21,b22,b23,b30,b31,b32,b33;
#define LD4(V0,V1,V2,V3,R) { int rr_ = (R); \
        V0 = maskW[(rr_<<2)+0]; V1 = maskW[(rr_<<2)+1]; \
        V2 = maskW[(rr_<<2)+2]; V3 = maskW[(rr_<<2)+3]; }
#define PRX(RWG, BIT, M0,M1,M2,M3, ROW) \
        if (!full && !(((RWG) >> (BIT)) & 1ULL)) { \
          rw0 |= (M0); rw1 |= (M1); rw2 |= (M2); rw3 |= (M3); \
          if (lane == 0) survRows[scW] = (u32)(base + (ROW)); \
          ++scW; full = (scW >= Kcap); \
        }
#define SWEEPG(G, RWG) \
        if (!full && (((G) << 6) < RL)) { \
          const int rb = (G) << 6; \
          LD4(a00,a01,a02,a03, rb+0) LD4(a10,a11,a12,a13, rb+1) \
          LD4(a20,a21,a22,a23, rb+2) LD4(a30,a31,a32,a33, rb+3) \
          for (int bb = 0; bb < 64 && !full; bb += 4) { \
            LD4(b00,b01,b02,b03, rb+bb+4) LD4(b10,b11,b12,b13, rb+bb+5) \
            LD4(b20,b21,b22,b23, rb+bb+6) LD4(b30,b31,b32,b33, rb+bb+7) \
            PRX(RWG, bb+0, a00,a01,a02,a03, rb+bb+0) \
            PRX(RWG, bb+1, a10,a11,a12,a13, rb+bb+1) \
            PRX(RWG, bb+2, a20,a21,a22,a23, rb+bb+2) \
            PRX(RWG, bb+3, a30,a31,a32,a33, rb+bb+3) \
            a00=b00;a01=b01;a02=b02;a03=b03; a10=b10;a11=b11;a12=b12;a13=b13; \
            a20=b20;a21=b21;a22=b22;a23=b23; a30=b30;a31=b31;a32=b32;a33=b33; \
          } \
        }
        SWEEPG(0, rw0) SWEEPG(1, rw1) SWEEPG(2, rw2) SWEEPG(3, rw3)
#undef SWEEPG
#undef PRX
#undef LD4
        if (lane == 0) scLds = scW;
      }
      __syncthreads();

      // parallel survivor fill (off the serial sweep path)
      {
        int scNew = scLds;
        if (tid >= sc && tid < scNew) {
          int wrow = (int)survRows[tid];
          int rr = wrow - base;          // this stage's local row
          sx0[tid] = bx0[rr]; sy0[tid] = by0[rr];
          sx1[tid] = bx1[rr]; sy1[tid] = by1[rr];
          sarea[tid] = areaA[rr];
          survKeyH[tid] = (u32)(skeyW64[wrow] >> 32);
        }
        __syncthreads();   // surv SoA complete before next stage / emit
        sc = scNew;
      }
    }

    minKey = skeyW64[Csel - 1];   // largest processed key (uniform read)
    processed += Csel;
    __syncthreads();
  }

  // ---- emit per-class survivor list (greedy order) ----
  if (tid < CPAD) {
    int o = cls * CPAD + tid;
    if (tid < sc) {
      cand[o] = ((u64)survKeyH[tid] << 32) | (u32)o;  // low32 == tie-order
      cbox[o] = make_float4(sx0[tid], sy0[tid], sx1[tid], sy1[tid]);
    } else {
      cand[o] = ~0ULL;
    }
  }

  // ---- signal completion; last block does the global top-K ----
  __threadfence();
  __syncthreads();
  if (tid == 0) lastSh = atomicAdd(done, 1u);
  __syncthreads();
  if (lastSh != NFG - 1) return;
  __threadfence();

  u64* kk = (u64*)LDSW;            // overlay (sort/mask regions dead)
  u64* ck = (u64*)(LDSW + 5120);   // overlay stage SoA (dead)
  if (tid == 0) cCnt = 0;
  if (tid < 256) { hist1[tid] = 0; hist2[tid] = 0; }
  __syncthreads();
  for (int t = tid; t < CTOT; t += NTHR) {
    u64 v = cand[t];
    kk[t] = v;
    if (v != ~0ULL) atomicAdd(&hist1[(int)(v >> 56)], 1);
  }
  __syncthreads();
  if (wid == 0) {                  // M = total valid count (wave reduce)
    int b4 = lane << 2;
    int s = hist1[b4] + hist1[b4 + 1] + hist1[b4 + 2] + hist1[b4 + 3];
    #pragma unroll
    for (int off = 32; off; off >>= 1) s += __shfl_xor(s, off);
    if (lane == 0) mSh = s;
  }
  __syncthreads();
  const int M = mSh;
  const int Kneed = (K < M) ? K : M;

  if (Kneed > 0) {
    if (wid == 0) bucket_select(hist1, Kneed, lane, &selB1, &selC1);
    __syncthreads();
    const int B1 = selB1, C1 = selC1;
    for (int t = tid; t < CTOT; t += NTHR) {
      u64 v = kk[t];
      if (v != ~0ULL && (int)(v >> 56) == B1)
        atomicAdd(&hist2[(int)((v >> 48) & 255)], 1);
    }
    __syncthreads();
    if (wid == 0) bucket_select(hist2, Kneed - C1, lane, &selB2, &selD2);
    __syncthreads();
    const int B2 = selB2;
    for (int t = tid; t < CTOT; t += NTHR) {   // compact contenders
      u64 v = kk[t];
      if (v == ~0ULL) continue;
      int b1 = (int)(v >> 56);
      int b2 = (int)((v >> 48) & 255);
      if (b1 < B1 || (b1 == B1 && b2 <= B2)) {
        int pos = atomicAdd(&cCnt, 1);
        if (pos < CSEL) ck[pos] = v;
      }
    }
    __syncthreads();
    const int C = cCnt;
    if (C <= CSEL) {
      // contender set downward-closed -> in-set rank == global rank
      if (tid < C) {
        u64 my = ck[tid];
        int rank = 0;
        for (int u = 0; u < C; ++u) rank += (ck[u] < my) ? 1 : 0;
        if (rank < K) {
          u32 flat = (u32)(my & 0xFFFFFFFFu);
          float score = key_to_float((u32)(my >> 32));
          int c2 = (int)(flat >> 7);
          float4 b = cbox[flat];
          out[rank * 4 + 0] = b.x;
          out[rank * 4 + 1] = b.y;
          out[rank * 4 + 2] = b.z;
          out[rank * 4 + 3] = b.w;
          out[K * 4 + rank] = (float)(c2 + 1);
          out[K * 5 + rank] = score;
        }
      }
    } else {
      // fallback: exact rank via 20 per-class binary searches
      for (int t = tid; t < CTOT; t += NTHR) {
        u64 kap = kk[t];
        if (kap == ~0ULL) continue;
        int rank = 0;
        #pragma unroll
        for (int cc2 = 0; cc2 < NFG; ++cc2) {
          const u64* a = kk + cc2 * CPAD;
          int lb = 0;
          #pragma unroll
          for (int s2 = CPAD >> 1; s2; s2 >>= 1) {
            int pq = lb + s2;
            if (a[pq - 1] < kap) lb = pq;
          }
          rank += lb;
        }
        if (rank < K) {
          u32 flat = (u32)(kap & 0xFFFFFFFFu);
          float score = key_to_float((u32)(kap >> 32));
          int c2 = (int)(flat >> 7);
          float4 b = cbox[flat];
          out[rank * 4 + 0] = b.x;
          out[rank * 4 + 1] = b.y;
          out[rank * 4 + 2] = b.z;
          out[rank * 4 + 3] = b.w;
          out[K * 4 + rank] = (float)(c2 + 1);
          out[K * 5 + rank] = score;
        }
      }
    }
  }
  __syncthreads();
  for (int r = tid; r < K; r += NTHR) {
    if (r >= M) {
      out[r * 4 + 0] = 0.0f; out[r * 4 + 1] = 0.0f;
      out[r * 4 + 2] = 1.0f; out[r * 4 + 3] = 1.0f;
      out[K * 4 + r] = 0.0f;
      out[K * 5 + r] = 0.0f;
    }
  }
}

// ---- launch ---------------------------------------------------------------
extern "C" void kernel_launch(void* const* d_in, const int* in_sizes, int n_in,
                              void* d_out, int out_size, void* d_ws, size_t ws_size,
                              hipStream_t stream) {
  const float* rois        = (const float*)d_in[0];
  const float* locs        = (const float*)d_in[1];
  const float* scores      = (const float*)d_in[2];
  const float* min_score   = (const float*)d_in[3];
  const float* max_overlap = (const float*)d_in[4];
  const int*   top_k       = (const int*)d_in[5];

  char* ws = (char*)d_ws;
  // layout: cand 2560*8 | cbox 2560*16 | probsT 20*2048*4 | decoded 2048*16 | done 4
  u64*    cand    = (u64*)ws;
  float4* cbox    = (float4*)(ws + 20480);
  float*  probsT  = (float*)(ws + 20480 + 40960);
  float4* decoded = (float4*)(ws + 20480 + 40960 + 163840);
  u32*    done    = (u32*)(ws + 20480 + 40960 + 163840 + 32768);

  k_decode<<<NROI / DROWS, 64, 0, stream>>>(rois, locs, scores, probsT, decoded, done);
  k_nms<<<NFG, NTHR, 0, stream>>>(probsT, decoded, min_score, max_overlap,
                                  cand, cbox, done, (float*)d_out, top_k);
}